// Round 3
// baseline (947.862 us; speedup 1.0000x reference)
//
#include <hip/hip_runtime.h>
#include <math.h>

#define NN 100000
#define NE 1000000
#define D  64
#define NB_SCAN 391   // ceil(NN/256)

// ================= CSR build (counting sort by dst) =================

__global__ __launch_bounds__(256) void k_hist(
    const int* __restrict__ dst, int* __restrict__ counts, int* __restrict__ rank)
{
    int e = blockIdx.x * 256 + threadIdx.x;
    if (e >= NE) return;
    rank[e] = atomicAdd(&counts[dst[e]], 1);
}

__global__ __launch_bounds__(256) void k_scan1(
    const int* __restrict__ counts, int* __restrict__ row_start, int* __restrict__ bsum)
{
    __shared__ int s[256];
    int t = threadIdx.x;
    int i = blockIdx.x * 256 + t;
    int v = (i < NN) ? counts[i] : 0;
    s[t] = v; __syncthreads();
#pragma unroll
    for (int off = 1; off < 256; off <<= 1) {
        int add = (t >= off) ? s[t - off] : 0;
        __syncthreads();
        s[t] += add;
        __syncthreads();
    }
    if (i < NN) row_start[i] = s[t] - v;       // local exclusive
    if (t == 255) bsum[blockIdx.x] = s[255];   // block total
}

__global__ __launch_bounds__(512) void k_scan2(
    const int* __restrict__ bsum, int* __restrict__ boff, int* __restrict__ row_start)
{
    __shared__ int s[512];
    int t = threadIdx.x;
    int v = (t < NB_SCAN) ? bsum[t] : 0;
    s[t] = v; __syncthreads();
#pragma unroll
    for (int off = 1; off < 512; off <<= 1) {
        int add = (t >= off) ? s[t - off] : 0;
        __syncthreads();
        s[t] += add;
        __syncthreads();
    }
    if (t < NB_SCAN) boff[t] = s[t] - v;       // exclusive block offsets
    if (t == 0) row_start[NN] = NE;
}

__global__ __launch_bounds__(256) void k_scan3(
    int* __restrict__ row_start, const int* __restrict__ boff)
{
    int i = blockIdx.x * 256 + threadIdx.x;
    if (i < NN) row_start[i] += boff[i >> 8];
}

__global__ __launch_bounds__(256) void k_scatter(
    const int* __restrict__ dst, const int* __restrict__ src,
    const int* __restrict__ perm, const int* __restrict__ rank,
    const int* __restrict__ row_start, int4* __restrict__ sorted)
{
    int e = blockIdx.x * 256 + threadIdx.x;
    if (e >= NE) return;
    int pos = row_start[dst[e]] + rank[e];
    sorted[pos] = make_int4(src[e], e, perm[e], 0);   // single 16B line-local write
}

// ============ one-time weight fold (linear msg path => combined mats) ======
// msg has NO activation, mean is linear  =>  msg·Wa2 folds:
//   C1t[k][j] = sum_l Wmsg[l][k]   * Wap[j][64+l]   (k<64, Hsum path)
//   C2t[k][j] = sum_l Wmsg[l][64+k]* Wap[j][64+l]   (k<64, Esum path)
//   bw[j]     = sum_l bmsg[l]      * Wap[j][64+l]
//   Wa1t[k][j]= Wap[j][k]
// Hout = relu( Hprev·Wa1t + inv*(Hsum·C1t + Esum·C2t + cnt*bw) + bap )
__global__ __launch_bounds__(256) void k_prep(
    const float* __restrict__ Wmsg, const float* __restrict__ bmsg,
    const float* __restrict__ Wap,
    float* __restrict__ Wa1t, float* __restrict__ C1t,
    float* __restrict__ C2t, float* __restrict__ bw)
{
    __shared__ float sWm[128][65];   // sWm[k][l] = Wmsg[l][k]
    __shared__ float sWa2[64][65];   // sWa2[l][j] = Wap[j][64+l]
    int t = threadIdx.x;
#pragma unroll 1
    for (int g = 0; g < 32; ++g) {
        int idx = g * 256 + t;       // 8192
        int l = idx >> 7, k = idx & 127;
        sWm[k][l] = Wmsg[l * 128 + k];
    }
#pragma unroll 1
    for (int g = 0; g < 16; ++g) {
        int idx = g * 256 + t;       // 4096
        int j = idx >> 6, l = idx & 63;
        sWa2[l][j] = Wap[j * 128 + 64 + l];
    }
    __syncthreads();
    int j = t & 63, kg = t >> 6;     // kg in 0..3
#pragma unroll 1
    for (int kk = 0; kk < 16; ++kk) {
        int k = kg * 16 + kk;
        float c1 = 0.f, c2 = 0.f;
#pragma unroll 1
        for (int l = 0; l < 64; ++l) {
            float w2 = sWa2[l][j];
            c1 += sWm[k][l] * w2;
            c2 += sWm[64 + k][l] * w2;
        }
        C1t[k * 64 + j] = c1;
        C2t[k * 64 + j] = c2;
        Wa1t[k * 64 + j] = Wap[j * 128 + k];
    }
    if (kg == 0) {
        float b = 0.f;
#pragma unroll 1
        for (int l = 0; l < 64; ++l) b += bmsg[l] * sWa2[l][j];
        bw[j] = b;
    }
}

// ================= pull-based segment sums (no atomics) =================

__global__ __launch_bounds__(256) void pull_pass1(
    const int4* __restrict__ sorted, const int* __restrict__ row_start,
    const float* __restrict__ nfeats, const float* __restrict__ efeats,
    float* __restrict__ hsum0, float* __restrict__ efsP, float* __restrict__ efsN)
{
    int gt = blockIdx.x * 256 + threadIdx.x;
    int w = gt >> 6, lane = gt & 63;
    if (w >= NN) return;
    int es = lane >> 4, c4 = (lane & 15) << 2;
    int beg = row_start[w], end = row_start[w + 1];

    float an0 = 0.f, an1 = 0.f, an2 = 0.f, an3 = 0.f;
    float ap0 = 0.f, ap1 = 0.f, ap2 = 0.f, ap3 = 0.f;
    float ag0 = 0.f, ag1 = 0.f, ag2 = 0.f, ag3 = 0.f;
    int i = beg + es;
    int4 q = (i < end) ? sorted[i] : make_int4(0, 0, 0, 0);
#pragma unroll 1
    for (; i < end; i += 4) {
        int inext = i + 4;
        int4 qn = (inext < end) ? sorted[inext] : make_int4(0, 0, 0, 0);
        float4 n  = *(const float4*)(nfeats + (size_t)q.x * D + c4);
        float4 ep = *(const float4*)(efeats + (size_t)q.y * D + c4);
        float4 en = *(const float4*)(efeats + (size_t)q.z * D + c4);
        an0 += n.x;  an1 += n.y;  an2 += n.z;  an3 += n.w;
        ap0 += ep.x; ap1 += ep.y; ap2 += ep.z; ap3 += ep.w;
        ag0 += en.x; ag1 += en.y; ag2 += en.z; ag3 += en.w;
        q = qn;
    }
#pragma unroll
    for (int off = 16; off <= 32; off <<= 1) {
        an0 += __shfl_xor(an0, off, 64); an1 += __shfl_xor(an1, off, 64);
        an2 += __shfl_xor(an2, off, 64); an3 += __shfl_xor(an3, off, 64);
        ap0 += __shfl_xor(ap0, off, 64); ap1 += __shfl_xor(ap1, off, 64);
        ap2 += __shfl_xor(ap2, off, 64); ap3 += __shfl_xor(ap3, off, 64);
        ag0 += __shfl_xor(ag0, off, 64); ag1 += __shfl_xor(ag1, off, 64);
        ag2 += __shfl_xor(ag2, off, 64); ag3 += __shfl_xor(ag3, off, 64);
    }
    if (lane < 16) {
        *(float4*)(hsum0 + (size_t)w * D + c4) = make_float4(an0, an1, an2, an3);
        *(float4*)(efsP  + (size_t)w * D + c4) = make_float4(ap0, ap1, ap2, ap3);
        *(float4*)(efsN  + (size_t)w * D + c4) = make_float4(ag0, ag1, ag2, ag3);
    }
}

__global__ __launch_bounds__(256) void pull_h2(
    const int4* __restrict__ sorted, const int* __restrict__ row_start,
    const float* __restrict__ hP, const float* __restrict__ hN,
    float* __restrict__ hsumP, float* __restrict__ hsumN)
{
    int gt = blockIdx.x * 256 + threadIdx.x;
    int w = gt >> 6, lane = gt & 63;
    if (w >= NN) return;
    int es = lane >> 4, c4 = (lane & 15) << 2;
    int beg = row_start[w], end = row_start[w + 1];

    float p0 = 0.f, p1 = 0.f, p2 = 0.f, p3 = 0.f;
    float n0 = 0.f, n1 = 0.f, n2 = 0.f, n3 = 0.f;
    int i = beg + es;
    int s = (i < end) ? sorted[i].x : 0;
#pragma unroll 1
    for (; i < end; i += 4) {
        int inext = i + 4;
        int sn = (inext < end) ? sorted[inext].x : 0;
        float4 vP = *(const float4*)(hP + (size_t)s * D + c4);
        float4 vN = *(const float4*)(hN + (size_t)s * D + c4);
        p0 += vP.x; p1 += vP.y; p2 += vP.z; p3 += vP.w;
        n0 += vN.x; n1 += vN.y; n2 += vN.z; n3 += vN.w;
        s = sn;
    }
#pragma unroll
    for (int off = 16; off <= 32; off <<= 1) {
        p0 += __shfl_xor(p0, off, 64); p1 += __shfl_xor(p1, off, 64);
        p2 += __shfl_xor(p2, off, 64); p3 += __shfl_xor(p3, off, 64);
        n0 += __shfl_xor(n0, off, 64); n1 += __shfl_xor(n1, off, 64);
        n2 += __shfl_xor(n2, off, 64); n3 += __shfl_xor(n3, off, 64);
    }
    if (lane < 16) {
        *(float4*)(hsumP + (size_t)w * D + c4) = make_float4(p0, p1, p2, p3);
        *(float4*)(hsumN + (size_t)w * D + c4) = make_float4(n0, n1, n2, n3);
    }
}

// ================= folded SAGE layer kernels (fused5) =================
// All GEMMs are now 64x64x64 halves against one of {Wa1t, C1t, C2t}.
// l0: Hprev·Wa1 and Hsum·C1 are side-independent -> 4 gemms total.
// l1loss: 3 gemms per side, phase-major so each B matrix staged once.

__device__ __forceinline__ void gemm_h(
    float acc[4][4], const float (*As)[68], const float (*Bs)[68],
    int ty, int tx4)
{
#pragma unroll 1
    for (int k0 = 0; k0 < 64; k0 += 4) {
        float a[4][4];
        float4 bv[4];
#pragma unroll
        for (int i = 0; i < 4; ++i)
            *(float4*)&a[i][0] = *(const float4*)&As[ty + 16 * i][k0];
#pragma unroll
        for (int kk = 0; kk < 4; ++kk)
            bv[kk] = *(const float4*)&Bs[k0 + kk][tx4];
#pragma unroll
        for (int kk = 0; kk < 4; ++kk)
#pragma unroll
            for (int i = 0; i < 4; ++i) {
                acc[i][0] += a[i][kk] * bv[kk].x;
                acc[i][1] += a[i][kk] * bv[kk].y;
                acc[i][2] += a[i][kk] * bv[kk].z;
                acc[i][3] += a[i][kk] * bv[kk].w;
            }
    }
}

#define STAGE_A(SRC) { \
    _Pragma("unroll") \
    for (int g = 0; g < 4; ++g) { \
        int idx = g * 256 + tid; \
        int node = idx >> 4, c = (idx & 15) << 2; \
        int gn = block0 + node; \
        float4 v = make_float4(0.f, 0.f, 0.f, 0.f); \
        if (gn < NN) v = *(const float4*)((SRC) + (size_t)gn * D + c); \
        *(float4*)&As[node][c] = v; } }

// contiguous float4 copy of a 64x64 matrix into Bs[64][68]
#define STAGE_B64(PTR) { \
    _Pragma("unroll") \
    for (int g = 0; g < 4; ++g) { \
        int m = g * 256 + tid; \
        *(float4*)&Bs[m >> 4][(m & 15) << 2] = *(const float4*)((PTR) + m * 4); } }

// Layer 0, both encodes. accA (Hprev·Wa1) and accM (Hsum·C1) computed ONCE.
__global__ __launch_bounds__(256, 4) void fused5_l0(
    const float* __restrict__ Hsum, const float* __restrict__ EsumP,
    const float* __restrict__ EsumN, const float* __restrict__ Hprev,
    const int* __restrict__ counts,
    const float* __restrict__ Wa1t, const float* __restrict__ C1t,
    const float* __restrict__ C2t, const float* __restrict__ bw,
    const float* __restrict__ bap,
    float* __restrict__ HoutP, float* __restrict__ HoutN)
{
    __shared__ __align__(16) float As[64][68];    // 17.4 KB
    __shared__ __align__(16) float Bs[64][68];    // 17.4 KB
    int tid = threadIdx.x;
    int block0 = blockIdx.x * 64;
    int tx = tid & 15, ty = tid >> 4;
    int tx4 = tx << 2;

    float cnt[4], inv[4];
#pragma unroll
    for (int i = 0; i < 4; ++i) {
        int gn = block0 + ty + 16 * i;
        cnt[i] = (gn < NN) ? (float)counts[gn] : 0.f;
        inv[i] = 1.0f / fmaxf(cnt[i], 1.0f);
    }
    float bwv[4], bav[4];
#pragma unroll
    for (int j = 0; j < 4; ++j) { bwv[j] = bw[tx4 + j]; bav[j] = bap[tx4 + j]; }

    // P1: accA = Hprev · Wa1t   (shared)
    STAGE_B64(Wa1t);
    STAGE_A(Hprev);
    __syncthreads();
    float accA[4][4] = {};
    gemm_h(accA, As, Bs, ty, tx4);
    __syncthreads();

    // P2: accM = Hsum · C1t     (shared)
    STAGE_B64(C1t);
    STAGE_A(Hsum);
    __syncthreads();
    float accM[4][4] = {};
    gemm_h(accM, As, Bs, ty, tx4);
    __syncthreads();

    // P3: accE = EsumP · C2t -> write HoutP
    STAGE_B64(C2t);
    STAGE_A(EsumP);
    __syncthreads();
    float accE[4][4] = {};
    gemm_h(accE, As, Bs, ty, tx4);
#pragma unroll
    for (int i = 0; i < 4; ++i) {
        int gn = block0 + ty + 16 * i;
        if (gn >= NN) continue;
#pragma unroll
        for (int j = 0; j < 4; ++j) {
            float x = accA[i][j] + (accM[i][j] + accE[i][j] + cnt[i] * bwv[j]) * inv[i] + bav[j];
            HoutP[(size_t)gn * D + tx4 + j] = fmaxf(x, 0.f);
        }
    }
    __syncthreads();

    // P4: accE2 = EsumN · C2t (Bs unchanged) -> write HoutN
    STAGE_A(EsumN);
    __syncthreads();
    float accE2[4][4] = {};
    gemm_h(accE2, As, Bs, ty, tx4);
#pragma unroll
    for (int i = 0; i < 4; ++i) {
        int gn = block0 + ty + 16 * i;
        if (gn >= NN) continue;
#pragma unroll
        for (int j = 0; j < 4; ++j) {
            float x = accA[i][j] + (accM[i][j] + accE2[i][j] + cnt[i] * bwv[j]) * inv[i] + bav[j];
            HoutN[(size_t)gn * D + tx4 + j] = fmaxf(x, 0.f);
        }
    }
}

// Layer 1 + loss, both encodes. Phase-major: each B matrix staged once.
__global__ __launch_bounds__(256, 4) void fused5_l1loss(
    const float* __restrict__ HsumP, const float* __restrict__ HsumN,
    const float* __restrict__ EsumP, const float* __restrict__ EsumN,
    const float* __restrict__ HprevP, const float* __restrict__ HprevN,
    const int* __restrict__ counts,
    const float* __restrict__ Wa1t, const float* __restrict__ C1t,
    const float* __restrict__ C2t, const float* __restrict__ bw,
    const float* __restrict__ bap,
    float* __restrict__ loss_out)
{
    __shared__ __align__(16) float As[64][68];
    __shared__ __align__(16) float Bs[64][68];
    int tid = threadIdx.x;
    int block0 = blockIdx.x * 64;
    int tx = tid & 15, ty = tid >> 4;
    int tx4 = tx << 2;

    float cnt[4], inv[4];
#pragma unroll
    for (int i = 0; i < 4; ++i) {
        int gn = block0 + ty + 16 * i;
        cnt[i] = (gn < NN) ? (float)counts[gn] : 0.f;
        inv[i] = 1.0f / fmaxf(cnt[i], 1.0f);
    }
    float bwv[4], bav[4];
#pragma unroll
    for (int j = 0; j < 4; ++j) { bwv[j] = bw[tx4 + j]; bav[j] = bap[tx4 + j]; }

    float accP[4][4] = {}, accN[4][4] = {};
    float lsum = 0.f;

    // ---- phase C1: Hsum · C1t, both sides ----
    STAGE_B64(C1t);
    STAGE_A(HsumP);
    __syncthreads();
    gemm_h(accP, As, Bs, ty, tx4);
    __syncthreads();
    STAGE_A(HsumN);
    __syncthreads();
    gemm_h(accN, As, Bs, ty, tx4);
    __syncthreads();

    // ---- phase C2: Esum · C2t, both sides ----
    STAGE_B64(C2t);
    STAGE_A(EsumP);
    __syncthreads();
    gemm_h(accP, As, Bs, ty, tx4);
    __syncthreads();
    STAGE_A(EsumN);
    __syncthreads();
    gemm_h(accN, As, Bs, ty, tx4);
    __syncthreads();

    // ---- phase Wa1: Hprev · Wa1t, side P -> loss ----
    STAGE_B64(Wa1t);
    STAGE_A(HprevP);
    __syncthreads();
    float acc2[4][4] = {};
    gemm_h(acc2, As, Bs, ty, tx4);
#pragma unroll
    for (int i = 0; i < 4; ++i) {
        int gn = block0 + ty + 16 * i;
        if (gn >= NN) continue;
#pragma unroll
        for (int j = 0; j < 4; ++j) {
            float x = acc2[i][j] + (accP[i][j] + cnt[i] * bwv[j]) * inv[i] + bav[j];
            x = fmaxf(x, 0.f);
            lsum += log1pf(expf(-x));        // pos: softplus(-x)
        }
    }
    __syncthreads();

    // ---- side N -> loss ----
    STAGE_A(HprevN);
    __syncthreads();
    float acc2n[4][4] = {};
    gemm_h(acc2n, As, Bs, ty, tx4);
#pragma unroll
    for (int i = 0; i < 4; ++i) {
        int gn = block0 + ty + 16 * i;
        if (gn >= NN) continue;
#pragma unroll
        for (int j = 0; j < 4; ++j) {
            float x = acc2n[i][j] + (accN[i][j] + cnt[i] * bwv[j]) * inv[i] + bav[j];
            x = fmaxf(x, 0.f);
            lsum += log1pf(expf(-x)) + x;    // neg: softplus(x)
        }
    }

#pragma unroll
    for (int off2 = 32; off2; off2 >>= 1) lsum += __shfl_down(lsum, off2, 64);
    if ((tid & 63) == 0)
        unsafeAtomicAdd(loss_out, lsum * (1.0f / 6400000.0f)); // / (N*64)
}

// ================= launch =================
extern "C" void kernel_launch(void* const* d_in, const int* in_sizes, int n_in,
                              void* d_out, int out_size, void* d_ws, size_t ws_size,
                              hipStream_t stream) {
    (void)in_sizes; (void)n_in; (void)out_size; (void)ws_size;
    const float* nfeats = (const float*)d_in[0];
    const float* efeats = (const float*)d_in[1];
    const int*   src    = (const int*)d_in[2];
    const int*   dst    = (const int*)d_in[3];
    const int*   perm   = (const int*)d_in[4];
    const float* Wmsg0  = (const float*)d_in[5];
    const float* bmsg0  = (const float*)d_in[6];
    const float* Wap0   = (const float*)d_in[7];
    const float* bap0   = (const float*)d_in[8];
    const float* Wmsg1  = (const float*)d_in[9];
    const float* bmsg1  = (const float*)d_in[10];
    const float* Wap1   = (const float*)d_in[11];
    const float* bap1   = (const float*)d_in[12];
    float* out = (float*)d_out;

    // ---- workspace layout (16B-aligned chunks; d_ws is ~1 GB) ----
    const size_t NV = (size_t)NN * D;
    char* p = (char*)d_ws;
    int4* sorted   = (int4*)p;               p += (size_t)NE * 16;   // 16 MB
    int*  rank     = (int*)p;                p += (size_t)NE * 4;    // 4 MB
    int*  counts   = (int*)p;                p += ((NN + 15) & ~15) * 4;
    int*  rowst    = (int*)p;                p += ((NN + 16) & ~15) * 4;
    int*  bsum     = (int*)p;                p += 512 * 4;
    int*  boff     = (int*)p;                p += 512 * 4;
    float* efsP    = (float*)p;              p += NV * 4;            // 25.6 MB each
    float* efsN    = (float*)p;              p += NV * 4;
    float* hsum0   = (float*)p;              p += NV * 4;
    float* h1P     = (float*)p;              p += NV * 4;
    float* h1N     = (float*)p;              p += NV * 4;
    float* hsum1P  = (float*)p;              p += NV * 4;
    float* hsum1N  = (float*)p;              p += NV * 4;
    float* wa1t0   = (float*)p;              p += 4096 * 4;          // 16 KB each
    float* c1t0    = (float*)p;              p += 4096 * 4;
    float* c2t0    = (float*)p;              p += 4096 * 4;
    float* bw0     = (float*)p;              p += 64 * 4;
    float* wa1t1   = (float*)p;              p += 4096 * 4;
    float* c1t1    = (float*)p;              p += 4096 * 4;
    float* c2t1    = (float*)p;              p += 4096 * 4;
    float* bw1     = (float*)p;              p += 64 * 4;

    const int EGb = (NE + 255) / 256;        // 3907
    const int PGb = ((size_t)NN * 64 + 255) / 256;  // 25000
    const int NG  = (NN + 63) / 64;          // 1563

    hipMemsetAsync(counts, 0, (size_t)NN * 4, stream);
    hipMemsetAsync(d_out, 0, 4, stream);

    // ---- one-time weight fold (tiny) ----
    k_prep<<<1, 256, 0, stream>>>(Wmsg0, bmsg0, Wap0, wa1t0, c1t0, c2t0, bw0);
    k_prep<<<1, 256, 0, stream>>>(Wmsg1, bmsg1, Wap1, wa1t1, c1t1, c2t1, bw1);

    // ---- CSR build ----
    k_hist<<<EGb, 256, 0, stream>>>(dst, counts, rank);
    k_scan1<<<NB_SCAN, 256, 0, stream>>>(counts, rowst, bsum);
    k_scan2<<<1, 512, 0, stream>>>(bsum, boff, rowst);
    k_scan3<<<NB_SCAN, 256, 0, stream>>>(rowst, boff);
    k_scatter<<<EGb, 256, 0, stream>>>(dst, src, perm, rank, rowst, sorted);

    // ---- all first-layer segment sums in one pass ----
    pull_pass1<<<PGb, 256, 0, stream>>>(sorted, rowst, nfeats, efeats, hsum0, efsP, efsN);

    // ---- layer 0 folded (shared accA + accM) ----
    fused5_l0<<<NG, 256, 0, stream>>>(hsum0, efsP, efsN, nfeats, counts,
                                      wa1t0, c1t0, c2t0, bw0, bap0, h1P, h1N);

    // ---- one dual pull for both encodes' h1 ----
    pull_h2<<<PGb, 256, 0, stream>>>(sorted, rowst, h1P, h1N, hsum1P, hsum1N);

    // ---- layer 1 + both losses in one dispatch ----
    fused5_l1loss<<<NG, 256, 0, stream>>>(hsum1P, hsum1N, efsP, efsN, h1P, h1N,
                                          counts, wa1t1, c1t1, c2t1, bw1, bap1, out);
}

// Round 5
// 841.518 us; speedup vs baseline: 1.1264x; 1.1264x over previous
//
#include <hip/hip_runtime.h>
#include <math.h>

#define NN 100000
#define NE 1000000
#define D  64
#define NB_SCAN 391   // ceil(NN/256)

// ================= CSR build (counting sort by dst) =================

__global__ __launch_bounds__(256) void k_hist(
    const int* __restrict__ dst, int* __restrict__ counts, int* __restrict__ rank)
{
    int e = blockIdx.x * 256 + threadIdx.x;
    if (e >= NE) return;
    rank[e] = atomicAdd(&counts[dst[e]], 1);
}

__global__ __launch_bounds__(256) void k_scan1(
    const int* __restrict__ counts, int* __restrict__ row_start, int* __restrict__ bsum)
{
    __shared__ int s[256];
    int t = threadIdx.x;
    int i = blockIdx.x * 256 + t;
    int v = (i < NN) ? counts[i] : 0;
    s[t] = v; __syncthreads();
#pragma unroll
    for (int off = 1; off < 256; off <<= 1) {
        int add = (t >= off) ? s[t - off] : 0;
        __syncthreads();
        s[t] += add;
        __syncthreads();
    }
    if (i < NN) row_start[i] = s[t] - v;       // local exclusive
    if (t == 255) bsum[blockIdx.x] = s[255];   // block total
}

__global__ __launch_bounds__(512) void k_scan2(
    const int* __restrict__ bsum, int* __restrict__ boff, int* __restrict__ row_start)
{
    __shared__ int s[512];
    int t = threadIdx.x;
    int v = (t < NB_SCAN) ? bsum[t] : 0;
    s[t] = v; __syncthreads();
#pragma unroll
    for (int off = 1; off < 512; off <<= 1) {
        int add = (t >= off) ? s[t - off] : 0;
        __syncthreads();
        s[t] += add;
        __syncthreads();
    }
    if (t < NB_SCAN) boff[t] = s[t] - v;       // exclusive block offsets
    if (t == 0) row_start[NN] = NE;
}

__global__ __launch_bounds__(256) void k_scan3(
    int* __restrict__ row_start, const int* __restrict__ boff)
{
    int i = blockIdx.x * 256 + threadIdx.x;
    if (i < NN) row_start[i] += boff[i >> 8];
}

__global__ __launch_bounds__(256) void k_scatter(
    const int* __restrict__ dst, const int* __restrict__ src,
    const int* __restrict__ perm, const int* __restrict__ rank,
    const int* __restrict__ row_start, int4* __restrict__ sorted)
{
    int e = blockIdx.x * 256 + threadIdx.x;
    if (e >= NE) return;
    int pos = row_start[dst[e]] + rank[e];
    sorted[pos] = make_int4(src[e], e, perm[e], 0);   // single 16B line-local write
}

// ============ one-time weight fold (linear msg path => combined mats) ======
// msg has NO activation, mean is linear  =>  msg·Wa2 folds:
//   C1t[k][j] = sum_l Wmsg[l][k]   * Wap[j][64+l]   (k<64, Hsum path)
//   C2t[k][j] = sum_l Wmsg[l][64+k]* Wap[j][64+l]   (k<64, Esum path)
//   bw[j]     = sum_l bmsg[l]      * Wap[j][64+l]
//   Wa1t[k][j]= Wap[j][k]
// Hout = relu( Hprev·Wa1t + inv*(Hsum·C1t + Esum·C2t + cnt*bw) + bap )
//
// R4: parallel version. R3's single-block scalar-LDS k_prep was ~15-30us
// SERIAL on one CU (255 idle) — Guideline-1 violation. Here: 16 blocks,
// lanes vary k -> both Wmsg row reads are contiguous 256B wave loads,
// Wap read is a same-address broadcast. No LDS, no barriers. ~3us.
__global__ __launch_bounds__(256) void k_prep_par(
    const float* __restrict__ Wmsg, const float* __restrict__ bmsg,
    const float* __restrict__ Wap,
    float* __restrict__ Wa1t, float* __restrict__ C1t,
    float* __restrict__ C2t, float* __restrict__ bw)
{
    int id = blockIdx.x * 256 + threadIdx.x;   // 16 blocks -> 4096 = 64x64
    int j = id >> 6, k = id & 63;              // lanes vary k
    float c1 = 0.f, c2 = 0.f;
#pragma unroll 4
    for (int l = 0; l < 64; ++l) {
        float w2 = Wap[j * 128 + 64 + l];      // wave-uniform broadcast
        c1 += Wmsg[l * 128 + k] * w2;          // contiguous across lanes
        c2 += Wmsg[l * 128 + 64 + k] * w2;
    }
    C1t[k * 64 + j] = c1;                      // one-time scatter stores
    C2t[k * 64 + j] = c2;
    Wa1t[k * 64 + j] = Wap[j * 128 + k];
    if (id < 64) {                             // bw[j] for j = id
        float b = 0.f;
#pragma unroll 4
        for (int l = 0; l < 64; ++l) b += bmsg[l] * Wap[id * 128 + 64 + l];
        bw[id] = b;
    }
}

// ================= pull-based segment sums (no atomics) =================

__global__ __launch_bounds__(256) void pull_pass1(
    const int4* __restrict__ sorted, const int* __restrict__ row_start,
    const float* __restrict__ nfeats, const float* __restrict__ efeats,
    float* __restrict__ hsum0, float* __restrict__ efsP, float* __restrict__ efsN)
{
    int gt = blockIdx.x * 256 + threadIdx.x;
    int w = gt >> 6, lane = gt & 63;
    if (w >= NN) return;
    int es = lane >> 4, c4 = (lane & 15) << 2;
    int beg = row_start[w], end = row_start[w + 1];

    float an0 = 0.f, an1 = 0.f, an2 = 0.f, an3 = 0.f;
    float ap0 = 0.f, ap1 = 0.f, ap2 = 0.f, ap3 = 0.f;
    float ag0 = 0.f, ag1 = 0.f, ag2 = 0.f, ag3 = 0.f;
    int i = beg + es;
    int4 q = (i < end) ? sorted[i] : make_int4(0, 0, 0, 0);
#pragma unroll 1
    for (; i < end; i += 4) {
        int inext = i + 4;
        int4 qn = (inext < end) ? sorted[inext] : make_int4(0, 0, 0, 0);
        float4 n  = *(const float4*)(nfeats + (size_t)q.x * D + c4);
        float4 ep = *(const float4*)(efeats + (size_t)q.y * D + c4);
        float4 en = *(const float4*)(efeats + (size_t)q.z * D + c4);
        an0 += n.x;  an1 += n.y;  an2 += n.z;  an3 += n.w;
        ap0 += ep.x; ap1 += ep.y; ap2 += ep.z; ap3 += ep.w;
        ag0 += en.x; ag1 += en.y; ag2 += en.z; ag3 += en.w;
        q = qn;
    }
#pragma unroll
    for (int off = 16; off <= 32; off <<= 1) {
        an0 += __shfl_xor(an0, off, 64); an1 += __shfl_xor(an1, off, 64);
        an2 += __shfl_xor(an2, off, 64); an3 += __shfl_xor(an3, off, 64);
        ap0 += __shfl_xor(ap0, off, 64); ap1 += __shfl_xor(ap1, off, 64);
        ap2 += __shfl_xor(ap2, off, 64); ap3 += __shfl_xor(ap3, off, 64);
        ag0 += __shfl_xor(ag0, off, 64); ag1 += __shfl_xor(ag1, off, 64);
        ag2 += __shfl_xor(ag2, off, 64); ag3 += __shfl_xor(ag3, off, 64);
    }
    if (lane < 16) {
        *(float4*)(hsum0 + (size_t)w * D + c4) = make_float4(an0, an1, an2, an3);
        *(float4*)(efsP  + (size_t)w * D + c4) = make_float4(ap0, ap1, ap2, ap3);
        *(float4*)(efsN  + (size_t)w * D + c4) = make_float4(ag0, ag1, ag2, ag3);
    }
}

__global__ __launch_bounds__(256) void pull_h2(
    const int4* __restrict__ sorted, const int* __restrict__ row_start,
    const float* __restrict__ hP, const float* __restrict__ hN,
    float* __restrict__ hsumP, float* __restrict__ hsumN)
{
    int gt = blockIdx.x * 256 + threadIdx.x;
    int w = gt >> 6, lane = gt & 63;
    if (w >= NN) return;
    int es = lane >> 4, c4 = (lane & 15) << 2;
    int beg = row_start[w], end = row_start[w + 1];

    float p0 = 0.f, p1 = 0.f, p2 = 0.f, p3 = 0.f;
    float n0 = 0.f, n1 = 0.f, n2 = 0.f, n3 = 0.f;
    int i = beg + es;
    int s = (i < end) ? sorted[i].x : 0;
#pragma unroll 1
    for (; i < end; i += 4) {
        int inext = i + 4;
        int sn = (inext < end) ? sorted[inext].x : 0;
        float4 vP = *(const float4*)(hP + (size_t)s * D + c4);
        float4 vN = *(const float4*)(hN + (size_t)s * D + c4);
        p0 += vP.x; p1 += vP.y; p2 += vP.z; p3 += vP.w;
        n0 += vN.x; n1 += vN.y; n2 += vN.z; n3 += vN.w;
        s = sn;
    }
#pragma unroll
    for (int off = 16; off <= 32; off <<= 1) {
        p0 += __shfl_xor(p0, off, 64); p1 += __shfl_xor(p1, off, 64);
        p2 += __shfl_xor(p2, off, 64); p3 += __shfl_xor(p3, off, 64);
        n0 += __shfl_xor(n0, off, 64); n1 += __shfl_xor(n1, off, 64);
        n2 += __shfl_xor(n2, off, 64); n3 += __shfl_xor(n3, off, 64);
    }
    if (lane < 16) {
        *(float4*)(hsumP + (size_t)w * D + c4) = make_float4(p0, p1, p2, p3);
        *(float4*)(hsumN + (size_t)w * D + c4) = make_float4(n0, n1, n2, n3);
    }
}

// ================= folded SAGE layer kernels (fused5) =================
// All GEMMs are 64x64x64 halves against one of {Wa1t, C1t, C2t}.
// l0: Hprev·Wa1 and Hsum·C1 are side-independent -> 4 gemms total.
// l1loss: 3 gemms per side, phase-major so each B matrix staged once.

__device__ __forceinline__ void gemm_h(
    float acc[4][4], const float (*As)[68], const float (*Bs)[68],
    int ty, int tx4)
{
#pragma unroll 1
    for (int k0 = 0; k0 < 64; k0 += 4) {
        float a[4][4];
        float4 bv[4];
#pragma unroll
        for (int i = 0; i < 4; ++i)
            *(float4*)&a[i][0] = *(const float4*)&As[ty + 16 * i][k0];
#pragma unroll
        for (int kk = 0; kk < 4; ++kk)
            bv[kk] = *(const float4*)&Bs[k0 + kk][tx4];
#pragma unroll
        for (int kk = 0; kk < 4; ++kk)
#pragma unroll
            for (int i = 0; i < 4; ++i) {
                acc[i][0] += a[i][kk] * bv[kk].x;
                acc[i][1] += a[i][kk] * bv[kk].y;
                acc[i][2] += a[i][kk] * bv[kk].z;
                acc[i][3] += a[i][kk] * bv[kk].w;
            }
    }
}

#define STAGE_A(SRC) { \
    _Pragma("unroll") \
    for (int g = 0; g < 4; ++g) { \
        int idx = g * 256 + tid; \
        int node = idx >> 4, c = (idx & 15) << 2; \
        int gn = block0 + node; \
        float4 v = make_float4(0.f, 0.f, 0.f, 0.f); \
        if (gn < NN) v = *(const float4*)((SRC) + (size_t)gn * D + c); \
        *(float4*)&As[node][c] = v; } }

// contiguous float4 copy of a 64x64 matrix into Bs[64][68]
#define STAGE_B64(PTR) { \
    _Pragma("unroll") \
    for (int g = 0; g < 4; ++g) { \
        int m = g * 256 + tid; \
        *(float4*)&Bs[m >> 4][(m & 15) << 2] = *(const float4*)((PTR) + m * 4); } }

// Layer 0, both encodes. accA (Hprev·Wa1) and accM (Hsum·C1) computed ONCE.
__global__ __launch_bounds__(256, 4) void fused5_l0(
    const float* __restrict__ Hsum, const float* __restrict__ EsumP,
    const float* __restrict__ EsumN, const float* __restrict__ Hprev,
    const int* __restrict__ counts,
    const float* __restrict__ Wa1t, const float* __restrict__ C1t,
    const float* __restrict__ C2t, const float* __restrict__ bw,
    const float* __restrict__ bap,
    float* __restrict__ HoutP, float* __restrict__ HoutN)
{
    __shared__ __align__(16) float As[64][68];    // 17.4 KB
    __shared__ __align__(16) float Bs[64][68];    // 17.4 KB
    int tid = threadIdx.x;
    int block0 = blockIdx.x * 64;
    int tx = tid & 15, ty = tid >> 4;
    int tx4 = tx << 2;

    float cnt[4], inv[4];
#pragma unroll
    for (int i = 0; i < 4; ++i) {
        int gn = block0 + ty + 16 * i;
        cnt[i] = (gn < NN) ? (float)counts[gn] : 0.f;
        inv[i] = 1.0f / fmaxf(cnt[i], 1.0f);
    }
    float bwv[4], bav[4];
#pragma unroll
    for (int j = 0; j < 4; ++j) { bwv[j] = bw[tx4 + j]; bav[j] = bap[tx4 + j]; }

    // P1: accA = Hprev · Wa1t   (shared)
    STAGE_B64(Wa1t);
    STAGE_A(Hprev);
    __syncthreads();
    float accA[4][4] = {};
    gemm_h(accA, As, Bs, ty, tx4);
    __syncthreads();

    // P2: accM = Hsum · C1t     (shared)
    STAGE_B64(C1t);
    STAGE_A(Hsum);
    __syncthreads();
    float accM[4][4] = {};
    gemm_h(accM, As, Bs, ty, tx4);
    __syncthreads();

    // P3: accE = EsumP · C2t -> write HoutP
    STAGE_B64(C2t);
    STAGE_A(EsumP);
    __syncthreads();
    float accE[4][4] = {};
    gemm_h(accE, As, Bs, ty, tx4);
#pragma unroll
    for (int i = 0; i < 4; ++i) {
        int gn = block0 + ty + 16 * i;
        if (gn >= NN) continue;
#pragma unroll
        for (int j = 0; j < 4; ++j) {
            float x = accA[i][j] + (accM[i][j] + accE[i][j] + cnt[i] * bwv[j]) * inv[i] + bav[j];
            HoutP[(size_t)gn * D + tx4 + j] = fmaxf(x, 0.f);
        }
    }
    __syncthreads();

    // P4: accE2 = EsumN · C2t (Bs unchanged) -> write HoutN
    STAGE_A(EsumN);
    __syncthreads();
    float accE2[4][4] = {};
    gemm_h(accE2, As, Bs, ty, tx4);
#pragma unroll
    for (int i = 0; i < 4; ++i) {
        int gn = block0 + ty + 16 * i;
        if (gn >= NN) continue;
#pragma unroll
        for (int j = 0; j < 4; ++j) {
            float x = accA[i][j] + (accM[i][j] + accE2[i][j] + cnt[i] * bwv[j]) * inv[i] + bav[j];
            HoutN[(size_t)gn * D + tx4 + j] = fmaxf(x, 0.f);
        }
    }
}

// Layer 1 + loss, both encodes. Phase-major: each B matrix staged once.
__global__ __launch_bounds__(256, 4) void fused5_l1loss(
    const float* __restrict__ HsumP, const float* __restrict__ HsumN,
    const float* __restrict__ EsumP, const float* __restrict__ EsumN,
    const float* __restrict__ HprevP, const float* __restrict__ HprevN,
    const int* __restrict__ counts,
    const float* __restrict__ Wa1t, const float* __restrict__ C1t,
    const float* __restrict__ C2t, const float* __restrict__ bw,
    const float* __restrict__ bap,
    float* __restrict__ loss_out)
{
    __shared__ __align__(16) float As[64][68];
    __shared__ __align__(16) float Bs[64][68];
    int tid = threadIdx.x;
    int block0 = blockIdx.x * 64;
    int tx = tid & 15, ty = tid >> 4;
    int tx4 = tx << 2;

    float cnt[4], inv[4];
#pragma unroll
    for (int i = 0; i < 4; ++i) {
        int gn = block0 + ty + 16 * i;
        cnt[i] = (gn < NN) ? (float)counts[gn] : 0.f;
        inv[i] = 1.0f / fmaxf(cnt[i], 1.0f);
    }
    float bwv[4], bav[4];
#pragma unroll
    for (int j = 0; j < 4; ++j) { bwv[j] = bw[tx4 + j]; bav[j] = bap[tx4 + j]; }

    float accP[4][4] = {}, accN[4][4] = {};
    float lsum = 0.f;

    // ---- phase C1: Hsum · C1t, both sides ----
    STAGE_B64(C1t);
    STAGE_A(HsumP);
    __syncthreads();
    gemm_h(accP, As, Bs, ty, tx4);
    __syncthreads();
    STAGE_A(HsumN);
    __syncthreads();
    gemm_h(accN, As, Bs, ty, tx4);
    __syncthreads();

    // ---- phase C2: Esum · C2t, both sides ----
    STAGE_B64(C2t);
    STAGE_A(EsumP);
    __syncthreads();
    gemm_h(accP, As, Bs, ty, tx4);
    __syncthreads();
    STAGE_A(EsumN);
    __syncthreads();
    gemm_h(accN, As, Bs, ty, tx4);
    __syncthreads();

    // ---- phase Wa1: Hprev · Wa1t, side P -> loss ----
    STAGE_B64(Wa1t);
    STAGE_A(HprevP);
    __syncthreads();
    float acc2[4][4] = {};
    gemm_h(acc2, As, Bs, ty, tx4);
#pragma unroll
    for (int i = 0; i < 4; ++i) {
        int gn = block0 + ty + 16 * i;
        if (gn >= NN) continue;
#pragma unroll
        for (int j = 0; j < 4; ++j) {
            float x = acc2[i][j] + (accP[i][j] + cnt[i] * bwv[j]) * inv[i] + bav[j];
            x = fmaxf(x, 0.f);
            lsum += log1pf(expf(-x));        // pos: softplus(-x)
        }
    }
    __syncthreads();

    // ---- side N -> loss ----
    STAGE_A(HprevN);
    __syncthreads();
    float acc2n[4][4] = {};
    gemm_h(acc2n, As, Bs, ty, tx4);
#pragma unroll
    for (int i = 0; i < 4; ++i) {
        int gn = block0 + ty + 16 * i;
        if (gn >= NN) continue;
#pragma unroll
        for (int j = 0; j < 4; ++j) {
            float x = acc2n[i][j] + (accN[i][j] + cnt[i] * bwv[j]) * inv[i] + bav[j];
            x = fmaxf(x, 0.f);
            lsum += log1pf(expf(-x)) + x;    // neg: softplus(x)
        }
    }

#pragma unroll
    for (int off2 = 32; off2; off2 >>= 1) lsum += __shfl_down(lsum, off2, 64);
    if ((tid & 63) == 0)
        unsafeAtomicAdd(loss_out, lsum * (1.0f / 6400000.0f)); // / (N*64)
}

// ================= launch =================
extern "C" void kernel_launch(void* const* d_in, const int* in_sizes, int n_in,
                              void* d_out, int out_size, void* d_ws, size_t ws_size,
                              hipStream_t stream) {
    (void)in_sizes; (void)n_in; (void)out_size; (void)ws_size;
    const float* nfeats = (const float*)d_in[0];
    const float* efeats = (const float*)d_in[1];
    const int*   src    = (const int*)d_in[2];
    const int*   dst    = (const int*)d_in[3];
    const int*   perm   = (const int*)d_in[4];
    const float* Wmsg0  = (const float*)d_in[5];
    const float* bmsg0  = (const float*)d_in[6];
    const float* Wap0   = (const float*)d_in[7];
    const float* bap0   = (const float*)d_in[8];
    const float* Wmsg1  = (const float*)d_in[9];
    const float* bmsg1  = (const float*)d_in[10];
    const float* Wap1   = (const float*)d_in[11];
    const float* bap1   = (const float*)d_in[12];
    float* out = (float*)d_out;

    // ---- workspace layout (16B-aligned chunks; d_ws is ~1 GB) ----
    const size_t NV = (size_t)NN * D;
    char* p = (char*)d_ws;
    int4* sorted   = (int4*)p;               p += (size_t)NE * 16;   // 16 MB
    int*  rank     = (int*)p;                p += (size_t)NE * 4;    // 4 MB
    int*  counts   = (int*)p;                p += ((NN + 15) & ~15) * 4;
    int*  rowst    = (int*)p;                p += ((NN + 16) & ~15) * 4;
    int*  bsum     = (int*)p;                p += 512 * 4;
    int*  boff     = (int*)p;                p += 512 * 4;
    float* efsP    = (float*)p;              p += NV * 4;            // 25.6 MB each
    float* efsN    = (float*)p;              p += NV * 4;
    float* hsum0   = (float*)p;              p += NV * 4;
    float* h1P     = (float*)p;              p += NV * 4;
    float* h1N     = (float*)p;              p += NV * 4;
    float* hsum1P  = (float*)p;              p += NV * 4;
    float* hsum1N  = (float*)p;              p += NV * 4;
    float* wa1t0   = (float*)p;              p += 4096 * 4;          // 16 KB each
    float* c1t0    = (float*)p;              p += 4096 * 4;
    float* c2t0    = (float*)p;              p += 4096 * 4;
    float* bw0     = (float*)p;              p += 64 * 4;
    float* wa1t1   = (float*)p;              p += 4096 * 4;
    float* c1t1    = (float*)p;              p += 4096 * 4;
    float* c2t1    = (float*)p;              p += 4096 * 4;
    float* bw1     = (float*)p;              p += 64 * 4;

    const int EGb = (NE + 255) / 256;        // 3907
    const int PGb = ((size_t)NN * 64 + 255) / 256;  // 25000
    const int NG  = (NN + 63) / 64;          // 1563

    hipMemsetAsync(counts, 0, (size_t)NN * 4, stream);
    hipMemsetAsync(d_out, 0, 4, stream);

    // ---- one-time weight fold (parallel, ~3us each) ----
    k_prep_par<<<16, 256, 0, stream>>>(Wmsg0, bmsg0, Wap0, wa1t0, c1t0, c2t0, bw0);
    k_prep_par<<<16, 256, 0, stream>>>(Wmsg1, bmsg1, Wap1, wa1t1, c1t1, c2t1, bw1);

    // ---- CSR build ----
    k_hist<<<EGb, 256, 0, stream>>>(dst, counts, rank);
    k_scan1<<<NB_SCAN, 256, 0, stream>>>(counts, rowst, bsum);
    k_scan2<<<1, 512, 0, stream>>>(bsum, boff, rowst);
    k_scan3<<<NB_SCAN, 256, 0, stream>>>(rowst, boff);
    k_scatter<<<EGb, 256, 0, stream>>>(dst, src, perm, rank, rowst, sorted);

    // ---- all first-layer segment sums in one pass ----
    pull_pass1<<<PGb, 256, 0, stream>>>(sorted, rowst, nfeats, efeats, hsum0, efsP, efsN);

    // ---- layer 0 folded (shared accA + accM) ----
    fused5_l0<<<NG, 256, 0, stream>>>(hsum0, efsP, efsN, nfeats, counts,
                                      wa1t0, c1t0, c2t0, bw0, bap0, h1P, h1N);

    // ---- one dual pull for both encodes' h1 ----
    pull_h2<<<PGb, 256, 0, stream>>>(sorted, rowst, h1P, h1N, hsum1P, hsum1N);

    // ---- layer 1 + both losses in one dispatch ----
    fused5_l1loss<<<NG, 256, 0, stream>>>(hsum1P, hsum1N, efsP, efsN, h1P, h1N,
                                          counts, wa1t1, c1t1, c2t1, bw1, bap1, out);
}